// Round 3
// baseline (304.205 us; speedup 1.0000x reference)
//
#include <hip/hip_runtime.h>
#include <math.h>

// Output row (70 floats): [coords(3) | enc(64) | colours(3)]
// enc[2j] = sin(i * 10^(-j/8)), enc[2j+1] = cos(...), j = 0..31
//
// v4: persistent pipelined blocks. grid = 2048 (8 blocks/CU), each block
// owns a contiguous chunk of ~16 tiles (32 rows each) and double-buffers
// LDS (2 x 8960 B = 17.9 KB -> still 8 blocks/CU):
//   iter: {prefetch next input (regs) | stream-store current tile |
//          compute next tile enc -> other buffer | one barrier}
// Store issue is continuous across the block lifetime instead of a ~2-iter
// burst per short-lived block; block launch/drain tails amortize 16x.
// enc math is bit-identical to v3 (which passed, absmax 0.0390625):
//   w = inv2pi * 10^(-j/8) via 5 conditional f64 literal muls,
//   t = row*w; frac = t - rint(t); sin/cos fed in REVOLUTIONS
//   (v_sin_f32 / v_cos_f32 native semantics).

#define TILE_ROWS 32
#define OUTC 70
#define TILE_FLOATS (TILE_ROWS * OUTC)      // 2240
#define TILE_V4     (TILE_FLOATS / 4)       // 560
#define TILE_IN     (TILE_ROWS * 6)         // 192
#define TILE_IN_V4  (TILE_IN / 4)           // 48
#define BLOCK 256
#define MAX_GRID 2048                        // 8 blocks/CU x 256 CU

__device__ __forceinline__ void prefetch_in(const float* __restrict__ pc, int t,
                                            long long in_total, int tid,
                                            float4& vin, bool& fast, long long& f0) {
    fast = false; f0 = 0;
    if (tid < TILE_IN_V4) {
        const long long inBase = (long long)t * TILE_IN;   // mult of 4
        f0 = inBase + tid * 4;
        if (f0 + 3 < in_total) {
            vin = reinterpret_cast<const float4*>(pc)[inBase / 4 + tid];
            fast = true;
        }
    }
}

__device__ __forceinline__ void compute_enc(float* __restrict__ buf, int t,
                                            int tid, int j, double w) {
    const int rowBase = t * TILE_ROWS;
    int r = tid >> 5;                        // local row 0..7, step 8
#pragma unroll
    for (int k = 0; k < 4; ++k) {
        const double tt = (double)(rowBase + r) * w;   // revolutions
        const double frac = tt - rint(tt);             // [-0.5, 0.5]
        const float fr = (float)frac;
        const int pos = r * OUTC + 3 + 2 * j;
        buf[pos]     = __builtin_amdgcn_sinf(fr);      // sin(2*pi*fr)
        buf[pos + 1] = __builtin_amdgcn_cosf(fr);      // cos(2*pi*fr)
        r += 8;
    }
}

__device__ __forceinline__ void scatter_in(float* __restrict__ buf,
                                           const float* __restrict__ pc,
                                           long long in_total, int tid,
                                           const float4& vin, bool fast, long long f0) {
    if (tid < TILE_IN_V4) {
        if (fast) {
            const float* ve = &vin.x;
#pragma unroll
            for (int m = 0; m < 4; ++m) {
                const int fl = tid * 4 + m;            // local input idx 0..191
                const int row = fl / 6;                // magic-mul
                const int c = fl - row * 6;
                const int col = (c < 3) ? c : (c + 64);
                buf[row * OUTC + col] = ve[m];
            }
        } else {                                       // ragged tail tile
            for (int m = 0; m < 4; ++m) {
                const long long f = f0 + m;
                if (f < in_total) {
                    const float val = pc[f];
                    const int fl = tid * 4 + m;
                    const int row = fl / 6;
                    const int c = fl - row * 6;
                    const int col = (c < 3) ? c : (c + 64);
                    buf[row * OUTC + col] = val;
                }
            }
        }
    }
}

__device__ __forceinline__ void store_tile(const float* __restrict__ buf,
                                           float* __restrict__ out, int t,
                                           long long total, int tid) {
    const long long outBase = (long long)t * TILE_FLOATS;   // mult of 4
    float4* __restrict__ out4 = reinterpret_cast<float4*>(out);
    if (outBase + TILE_FLOATS <= total) {
        // full tile: unguarded float4 stream (always taken for n = 1e6)
        for (int i = tid; i < TILE_V4; i += BLOCK) {
            float4 v;
            v.x = buf[i * 4 + 0];
            v.y = buf[i * 4 + 1];
            v.z = buf[i * 4 + 2];
            v.w = buf[i * 4 + 3];
            out4[outBase / 4 + i] = v;
        }
    } else {
        for (int i = tid; i < TILE_V4; i += BLOCK) {
            const long long g = outBase + (long long)i * 4;
            if (g + 4 <= total) {
                float4 v;
                v.x = buf[i * 4 + 0];
                v.y = buf[i * 4 + 1];
                v.z = buf[i * 4 + 2];
                v.w = buf[i * 4 + 3];
                out4[outBase / 4 + i] = v;
            } else {
                for (int m = 0; m < 4; ++m)
                    if (g + m < total) out[g + m] = buf[i * 4 + m];
            }
        }
    }
}

__global__ __launch_bounds__(256, 8) void pe_kernel(const float* __restrict__ pc,
                                                    float* __restrict__ out,
                                                    int n_rows, int tiles_per_block) {
    __shared__ float s_tile[2][TILE_FLOATS];   // 17920 B -> 8 blocks/CU

    const int tid = threadIdx.x;
    const int T = (n_rows + TILE_ROWS - 1) / TILE_ROWS;
    const int t0 = blockIdx.x * tiles_per_block;
    const int t1 = (t0 + tiles_per_block < T) ? (t0 + tiles_per_block) : T;
    if (t0 >= t1) return;

    // per-thread w = inv_two_pi * 10^(-j/8), j = tid & 31 (identical to v3)
    const int j = tid & 31;
    double w = 0.15915494309189533577;               // 1/(2*pi)
    if (j & 1)  w *= 0.74989420933245585;            // 10^(-1/8)
    if (j & 2)  w *= 0.5623413251903491;             // 10^(-1/4)
    if (j & 4)  w *= 0.31622776601683794;            // 10^(-1/2)
    if (j & 8)  w *= 0.1;                            // 10^(-1)
    if (j & 16) w *= 0.01;                           // 10^(-2)

    const long long in_total = (long long)n_rows * 6;
    const long long total    = (long long)n_rows * OUTC;

    // ---- prologue: fill buffer 0 with tile t0 ----
    {
        float4 vin; bool fast; long long f0;
        prefetch_in(pc, t0, in_total, tid, vin, fast, f0);
        compute_enc(s_tile[0], t0, tid, j, w);
        scatter_in(s_tile[0], pc, in_total, tid, vin, fast, f0);
    }
    __syncthreads();

    // ---- main pipeline: store buf[cur] for tile t, build buf[cur^1] for t+1 ----
    int cur = 0;
    for (int t = t0; t < t1; ++t) {
        const bool has_next = (t + 1 < t1);
        float4 vin; bool fast = false; long long f0 = 0;
        if (has_next) prefetch_in(pc, t + 1, in_total, tid, vin, fast, f0);  // vmem early
        store_tile(s_tile[cur], out, t, total, tid);                          // stream out
        if (has_next) {
            compute_enc(s_tile[cur ^ 1], t + 1, tid, j, w);                   // VALU covers
            scatter_in(s_tile[cur ^ 1], pc, in_total, tid, vin, fast, f0);    //  store drain
        }
        __syncthreads();
        cur ^= 1;
    }
}

extern "C" void kernel_launch(void* const* d_in, const int* in_sizes, int n_in,
                              void* d_out, int out_size, void* d_ws, size_t ws_size,
                              hipStream_t stream) {
    const float* pc = (const float*)d_in[0];
    float* out = (float*)d_out;
    const int n_rows = in_sizes[0] / 6;
    const int T = (n_rows + TILE_ROWS - 1) / TILE_ROWS;          // 31250
    int grid = (T < MAX_GRID) ? T : MAX_GRID;                    // 2048
    const int tpb = (T + grid - 1) / grid;                       // 16
    grid = (T + tpb - 1) / tpb;                                  // trim idle blocks
    pe_kernel<<<dim3(grid), dim3(BLOCK), 0, stream>>>(pc, out, n_rows, tpb);
}

// Round 4
// 292.671 us; speedup vs baseline: 1.0394x; 1.0394x over previous
//
#include <hip/hip_runtime.h>
#include <math.h>

// Output row (70 floats): [coords(3) | enc(64) | colours(3)]
// enc[2j] = sin(i * 10^(-j/8)), enc[2j+1] = cos(...), j = 0..31
//
// FINAL (revert to best-measured v1, 292.7/294.3 us harness-verified).
// Session conclusion: pe_kernel is write-roofline-bound. It moves 304 MB
// (280 MB store + 24 MB load) at the ~6 TB/s the in-graph fill kernel
// demonstrates on the same buffer => ~50 us. The remaining ~240 us of
// dur_us is harness reset (1.12 GB poison fill ~185 us + tiny dispatches).
// Structural levers tested and rejected: pure streaming (+40 us),
// 64-row blocks / no-exp / native-revolution sincos (neutral),
// persistent double-buffered pipeline (+7 us).
//
// Design: 32 rows per block staged in LDS (2240 floats = 560 float4s exactly;
// block global base 2240*b is float4-aligned even though the 70-float row
// stride is not). Phase A computes enc pairs divergence-free (1 sincos per
// 2 outputs, native __sinf/__cosf) + scatters coords/colours from coalesced
// float4 input loads. Phase B streams LDS -> global as aligned float4s.

#define ROWS_PER_BLOCK 32
#define OUTC 70
#define FLOATS_PER_BLOCK (ROWS_PER_BLOCK * OUTC)     // 2240
#define VEC4_PER_BLOCK   (FLOATS_PER_BLOCK / 4)      // 560
#define IN_FLOATS_PER_BLOCK (ROWS_PER_BLOCK * 6)     // 192
#define IN_VEC4_PER_BLOCK   (IN_FLOATS_PER_BLOCK/4)  // 48

__global__ __launch_bounds__(256) void pe_kernel(const float* __restrict__ pc,
                                                 float* __restrict__ out,
                                                 int n_rows) {
    __shared__ float  s_tile[FLOATS_PER_BLOCK];
    __shared__ double s_w2[32];          // 10^(-j/8) / (2*pi)

    const int tid = threadIdx.x;
    const int b = blockIdx.x;
    const int rowBase = b * ROWS_PER_BLOCK;

    if (tid < 32) {
        // inv_two_pi * 10000^(-tid/32); log() folds at compile time
        s_w2[tid] = 0.15915494309189533577 * exp(-(double)tid * (log(10000.0) / 32.0));
    }
    __syncthreads();

    // ---- Phase A1: enc pairs into LDS (uniform, no divergence) ----
    const int j = tid & 31;              // same j for all 4 pairs of this thread
    const double w2 = s_w2[j];
    const double two_pi = 6.2831853071795864769;
    int r = tid >> 5;                    // local row 0..7, step 8
#pragma unroll
    for (int k = 0; k < 4; ++k) {
        const double t = (double)(rowBase + r) * w2;   // revolutions
        const double frac = t - rint(t);               // [-0.5, 0.5]
        const float rad = (float)(frac * two_pi);      // [-pi, pi]
        const int pos = r * OUTC + 3 + 2 * j;
        s_tile[pos]     = __sinf(rad);                 // native v_sin_f32
        s_tile[pos + 1] = __cosf(rad);                 // native v_cos_f32
        r += 8;
    }

    // ---- Phase A2: coords + colours via coalesced float4 loads ----
    if (tid < IN_VEC4_PER_BLOCK) {
        const long long inBase = (long long)b * IN_FLOATS_PER_BLOCK;
        const long long f0 = inBase + tid * 4;
        const long long in_total = (long long)n_rows * 6;
        if (f0 + 3 < in_total) {
            const float4 v = reinterpret_cast<const float4*>(pc)[inBase / 4 + tid];
            const float* ve = &v.x;
#pragma unroll
            for (int m = 0; m < 4; ++m) {
                const int fl = tid * 4 + m;            // local input idx 0..191
                const int row = fl / 6;                // magic-mul
                const int c = fl - row * 6;
                const int col = (c < 3) ? c : (c + 64); // 67..69 for colours
                s_tile[row * OUTC + col] = ve[m];
            }
        } else {                                       // ragged tail block
            for (int m = 0; m < 4; ++m) {
                const long long f = f0 + m;
                if (f < in_total) {
                    const float val = pc[f];
                    const int fl = tid * 4 + m;
                    const int row = fl / 6;
                    const int c = fl - row * 6;
                    const int col = (c < 3) ? c : (c + 64);
                    s_tile[row * OUTC + col] = val;
                }
            }
        }
    }
    __syncthreads();

    // ---- Phase B: LDS tile -> global, 16B-aligned float4 stores ----
    const long long outBase = (long long)b * FLOATS_PER_BLOCK;  // multiple of 4
    const long long total = (long long)n_rows * OUTC;
    for (int i = tid; i < VEC4_PER_BLOCK; i += 256) {
        const long long g = outBase + (long long)i * 4;
        if (g + 4 <= total) {
            float4 v;
            v.x = s_tile[i * 4 + 0];
            v.y = s_tile[i * 4 + 1];
            v.z = s_tile[i * 4 + 2];
            v.w = s_tile[i * 4 + 3];
            reinterpret_cast<float4*>(out)[outBase / 4 + i] = v;
        } else {
            for (int m = 0; m < 4; ++m)
                if (g + m < total) out[g + m] = s_tile[i * 4 + m];
        }
    }
}

extern "C" void kernel_launch(void* const* d_in, const int* in_sizes, int n_in,
                              void* d_out, int out_size, void* d_ws, size_t ws_size,
                              hipStream_t stream) {
    const float* pc = (const float*)d_in[0];
    float* out = (float*)d_out;
    const int n_rows = in_sizes[0] / 6;
    const int grid = (n_rows + ROWS_PER_BLOCK - 1) / ROWS_PER_BLOCK;  // 31250
    pe_kernel<<<dim3(grid), dim3(256), 0, stream>>>(pc, out, n_rows);
}